// Round 2
// baseline (2025.106 us; speedup 1.0000x reference)
//
#include <hip/hip_runtime.h>

// ---------------------------------------------------------------------------
// StrongFormPhysicsLoss, round 2:
//   - pack the 4 gathered node arrays into one 64B-aligned [N][16] f32 block
//     (1 cache line per endpoint gather instead of 4+)
//   - AoS accumulator [N][16]: F_int[0:3], M_int[3:6], F_ext[6:9] so all 9
//     atomics per endpoint hit one 64B line (tests sector-coalescing of
//     scattered atomics)
// Fallback paths if ws_size is too small for the 128MB layout.
// ---------------------------------------------------------------------------

struct Scal {
    double rkin2, e1, e2, Lsum;          // element-level sums
    double Fe2, F2, Mr2, Mp2;            // node-level masked sums
    unsigned int qmax_bits, Lmax_bits;   // float-as-uint maxes (values >= 0)
    unsigned int cnt_d, cnt_r, cnt_p;    // mask counts
};

__device__ __forceinline__ double waveSumD(double v) {
#pragma unroll
    for (int o = 32; o > 0; o >>= 1) v += __shfl_down(v, o, 64);
    return v;
}
__device__ __forceinline__ float waveMaxF(float v) {
#pragma unroll
    for (int o = 32; o > 0; o >>= 1) v = fmaxf(v, __shfl_down(v, o, 64));
    return v;
}
__device__ __forceinline__ unsigned waveSumU(unsigned v) {
#pragma unroll
    for (int o = 32; o > 0; o >>= 1) v += __shfl_down(v, o, 64);
    return v;
}

// block = 256 threads = 4 waves
__device__ __forceinline__ void blockAtomicAddD(double v, double* dst, double* smem) {
    v = waveSumD(v);
    const int lane = threadIdx.x & 63, wid = threadIdx.x >> 6;
    if (lane == 0) smem[wid] = v;
    __syncthreads();
    if (threadIdx.x == 0) atomicAdd(dst, smem[0] + smem[1] + smem[2] + smem[3]);
    __syncthreads();
}
__device__ __forceinline__ void blockAtomicMaxF(float v, unsigned int* dst, float* smem) {
    v = waveMaxF(v);
    const int lane = threadIdx.x & 63, wid = threadIdx.x >> 6;
    if (lane == 0) smem[wid] = v;
    __syncthreads();
    if (threadIdx.x == 0) {
        float r = fmaxf(fmaxf(smem[0], smem[1]), fmaxf(smem[2], smem[3]));
        atomicMax(dst, __float_as_uint(fmaxf(r, 0.0f)));
    }
    __syncthreads();
}
__device__ __forceinline__ void blockAtomicAddU(unsigned v, unsigned int* dst, unsigned* smem) {
    v = waveSumU(v);
    const int lane = threadIdx.x & 63, wid = threadIdx.x >> 6;
    if (lane == 0) smem[wid] = v;
    __syncthreads();
    if (threadIdx.x == 0) atomicAdd(dst, smem[0] + smem[1] + smem[2] + smem[3]);
    __syncthreads();
}

// pack[k][0:3]=pred, [3:6]=grad_ux, [6:9]=grad_uz, [9:12]=grad_phi, [12:16] unused
__global__ __launch_bounds__(256) void pack_nodes(
    const float* __restrict__ pred, const float* __restrict__ gux,
    const float* __restrict__ guz,  const float* __restrict__ gphi,
    float* __restrict__ pack, int n)
{
    const int k = blockIdx.x * blockDim.x + threadIdx.x;
    if (k >= n) return;
    const size_t b3 = 3 * (size_t)k;
    float4 A = make_float4(pred[b3], pred[b3 + 1], pred[b3 + 2], gux[b3]);
    float4 B = make_float4(gux[b3 + 1], gux[b3 + 2], guz[b3], guz[b3 + 1]);
    float4 C = make_float4(guz[b3 + 2], gphi[b3], gphi[b3 + 1], gphi[b3 + 2]);
    float4* o = (float4*)(pack + 16 * (size_t)k);
    o[0] = A; o[1] = B; o[2] = C;   // o[3] untouched (saves write BW)
}

// MODE 2: packed gather + AoS acc; MODE 1: raw gather + AoS acc; MODE 0: raw + SoA
template <int MODE>
__global__ __launch_bounds__(256) void elem_pass(
    const float* __restrict__ pred, const float* __restrict__ grad_ux,
    const float* __restrict__ grad_uz, const float* __restrict__ grad_phi,
    const float* __restrict__ pack,
    const float* __restrict__ prop_E, const float* __restrict__ prop_A,
    const float* __restrict__ prop_I22, const float* __restrict__ elemL,
    const float* __restrict__ dirs, const float* __restrict__ load,
    const int* __restrict__ conn,
    float* __restrict__ acc,            // AoS base (MODE>=1) or F_int (MODE==0)
    float* __restrict__ M_soa, float* __restrict__ Fe_soa,
    Scal* sc, int n_elems)
{
    __shared__ double smD[4];
    __shared__ float  smF[4];

    double s_rkin2 = 0.0, s_e1 = 0.0, s_e2 = 0.0, s_Lsum = 0.0;
    float m_q = 0.0f, m_L = 0.0f;

    const int stride = gridDim.x * blockDim.x;
    for (int e = blockIdx.x * blockDim.x + threadIdx.x; e < n_elems; e += stride) {
        const int2 ij = ((const int2*)conn)[e];
        const int i = ij.x, j = ij.y;

        const float x0 = dirs[3 * e], x1 = dirs[3 * e + 1], x2 = dirs[3 * e + 2];

        // local axes
        const bool par = fabsf(x1) > 0.99f;
        float z0, z1, z2;
        if (par) { z0 = x1; z1 = -x0; z2 = 0.0f; }      // cross(x,(0,0,1))
        else     { z0 = -x2; z1 = 0.0f; z2 = x0; }      // cross(x,(0,1,0))
        float zn = fmaxf(sqrtf(z0 * z0 + z1 * z1 + z2 * z2), 1e-8f);
        z0 /= zn; z1 /= zn; z2 /= zn;
        float y0 = z1 * x2 - z2 * x1;
        float y1 = z2 * x0 - z0 * x2;
        float y2 = z0 * x1 - z1 * x0;
        float yn = fmaxf(sqrtf(y0 * y0 + y1 * y1 + y2 * y2), 1e-8f);
        y0 /= yn; y1 /= yn; y2 /= yn;

        // node gathers
        float uxi, uzi, phii, uxj, uzj, phij;
        float gxi, gzi, kap_i, gxj, gzj, kap_j;
        if (MODE == 2) {
            const float4* pi = (const float4*)(pack + 16 * (size_t)i);
            const float4 a = pi[0], b = pi[1], c = pi[2];
            uxi = a.x; uzi = a.y; phii = a.z;
            gxi   = a.w * x0 + b.x * x1 + b.y * x2;
            gzi   = b.z * x0 + b.w * x1 + c.x * x2;
            kap_i = c.y * x0 + c.z * x1 + c.w * x2;
            const float4* pj = (const float4*)(pack + 16 * (size_t)j);
            const float4 d = pj[0], f = pj[1], g = pj[2];
            uxj = d.x; uzj = d.y; phij = d.z;
            gxj   = d.w * x0 + f.x * x1 + f.y * x2;
            gzj   = f.z * x0 + f.w * x1 + g.x * x2;
            kap_j = g.y * x0 + g.z * x1 + g.w * x2;
        } else {
            uxi = pred[3 * i]; uzi = pred[3 * i + 1]; phii = pred[3 * i + 2];
            uxj = pred[3 * j]; uzj = pred[3 * j + 1]; phij = pred[3 * j + 2];
            gxi   = grad_ux[3 * i] * x0 + grad_ux[3 * i + 1] * x1 + grad_ux[3 * i + 2] * x2;
            gzi   = grad_uz[3 * i] * x0 + grad_uz[3 * i + 1] * x1 + grad_uz[3 * i + 2] * x2;
            kap_i = grad_phi[3 * i] * x0 + grad_phi[3 * i + 1] * x1 + grad_phi[3 * i + 2] * x2;
            gxj   = grad_ux[3 * j] * x0 + grad_ux[3 * j + 1] * x1 + grad_ux[3 * j + 2] * x2;
            gzj   = grad_uz[3 * j] * x0 + grad_uz[3 * j + 1] * x1 + grad_uz[3 * j + 2] * x2;
            kap_j = grad_phi[3 * j] * x0 + grad_phi[3 * j + 1] * x1 + grad_phi[3 * j + 2] * x2;
        }
        const float dux = uxj - uxi, duz = uzj - uzi;

        const float Le   = elemL[e];
        const float invL = 1.0f / Le;
        const float EA   = prop_E[e] * prop_A[e];
        const float EI   = prop_E[e] * prop_I22[e];

        const float du_ax  = dux * x0 + duz * x2;
        const float eps_fd = du_ax * invL;
        const float N_fd   = EA * eps_fd;
        const float du_tr  = dux * z0 + duz * z2;
        const float kappa_fd = (phij - phii) * invL;

        const float EIL = EI * invL, EIL2 = EIL * invL, EIL3 = EIL2 * invL;
        const float V_fd = 12.0f * EIL3 * du_tr - 6.0f * EIL2 * (phii + phij);
        const float M_yi = 6.0f * EIL2 * du_tr - EIL * (4.0f * phii + 2.0f * phij);
        const float M_yj = 6.0f * EIL2 * du_tr - EIL * (2.0f * phii + 4.0f * phij);

        const float eps_ag   = 0.5f * ((x0 * gxi + x2 * gzi) + (x0 * gxj + x2 * gzj));
        const float kappa_ag = 0.5f * (kap_i + kap_j);

        const float Fe0 = N_fd * x0 + V_fd * z0;
        const float Fe1 = N_fd * x1 + V_fd * z1;
        const float Fe2 = N_fd * x2 + V_fd * z2;

        const float l0 = load[3 * e], l1 = load[3 * e + 1], l2 = load[3 * e + 2];
        const float hl = 0.5f * Le;

        if (MODE >= 1) {
            float* ai = acc + 16 * (size_t)i;   // one 64B line
            atomicAdd(ai + 0, Fe0);
            atomicAdd(ai + 1, Fe1);
            atomicAdd(ai + 2, Fe2);
            atomicAdd(ai + 3, M_yi * y0);
            atomicAdd(ai + 4, M_yi * y1);
            atomicAdd(ai + 5, M_yi * y2);
            atomicAdd(ai + 6, l0 * hl);
            atomicAdd(ai + 7, l1 * hl);
            atomicAdd(ai + 8, l2 * hl);
            float* aj = acc + 16 * (size_t)j;   // one 64B line
            atomicAdd(aj + 0, -Fe0);
            atomicAdd(aj + 1, -Fe1);
            atomicAdd(aj + 2, -Fe2);
            atomicAdd(aj + 3, M_yj * y0);
            atomicAdd(aj + 4, M_yj * y1);
            atomicAdd(aj + 5, M_yj * y2);
            atomicAdd(aj + 6, l0 * hl);
            atomicAdd(aj + 7, l1 * hl);
            atomicAdd(aj + 8, l2 * hl);
        } else {
            atomicAdd(&acc[3 * i],     Fe0);
            atomicAdd(&acc[3 * i + 1], Fe1);
            atomicAdd(&acc[3 * i + 2], Fe2);
            atomicAdd(&acc[3 * j],     -Fe0);
            atomicAdd(&acc[3 * j + 1], -Fe1);
            atomicAdd(&acc[3 * j + 2], -Fe2);
            atomicAdd(&M_soa[3 * i],     M_yi * y0);
            atomicAdd(&M_soa[3 * i + 1], M_yi * y1);
            atomicAdd(&M_soa[3 * i + 2], M_yi * y2);
            atomicAdd(&M_soa[3 * j],     M_yj * y0);
            atomicAdd(&M_soa[3 * j + 1], M_yj * y1);
            atomicAdd(&M_soa[3 * j + 2], M_yj * y2);
            atomicAdd(&Fe_soa[3 * i],     l0 * hl);
            atomicAdd(&Fe_soa[3 * i + 1], l1 * hl);
            atomicAdd(&Fe_soa[3 * i + 2], l2 * hl);
            atomicAdd(&Fe_soa[3 * j],     l0 * hl);
            atomicAdd(&Fe_soa[3 * j + 1], l1 * hl);
            atomicAdd(&Fe_soa[3 * j + 2], l2 * hl);
        }

        // element-level reductions
        const float dw_ds = du_tr * invL;
        const float r_kin = 0.5f * (phii + phij) - dw_ds;
        s_rkin2 += (double)(r_kin * r_kin);
        const float d1 = eps_ag - eps_fd;
        s_e1 += (double)(d1 * d1);
        const float d2 = kappa_ag - kappa_fd;
        s_e2 += (double)(d2 * d2);
        s_Lsum += (double)Le;
        m_q = fmaxf(m_q, fmaxf(fabsf(l0), fmaxf(fabsf(l1), fabsf(l2))));
        m_L = fmaxf(m_L, Le);
    }

    blockAtomicAddD(s_rkin2, &sc->rkin2, smD);
    blockAtomicAddD(s_e1,    &sc->e1,    smD);
    blockAtomicAddD(s_e2,    &sc->e2,    smD);
    blockAtomicAddD(s_Lsum,  &sc->Lsum,  smD);
    blockAtomicMaxF(m_q, &sc->qmax_bits, smF);
    blockAtomicMaxF(m_L, &sc->Lmax_bits, smF);
}

template <bool AOS>
__global__ __launch_bounds__(256) void node_pass(
    const float* __restrict__ acc,      // AoS base, or F_int (SoA)
    const float* __restrict__ M_soa, const float* __restrict__ Fe_soa,
    const float* __restrict__ bc_disp, const float* __restrict__ bc_rot,
    Scal* sc, int n_nodes)
{
    __shared__ double smD[4];
    __shared__ unsigned smU[4];

    double sFe2 = 0.0, sF2 = 0.0, sMr2 = 0.0, sMp2 = 0.0;
    unsigned cd = 0, cr = 0, cp = 0;

    const int stride = gridDim.x * blockDim.x;
    for (int k = blockIdx.x * blockDim.x + threadIdx.x; k < n_nodes; k += stride) {
        const float bd = bc_disp[k], br = bc_rot[k];
        const bool free_d = bd < 0.5f;
        const bool free_r = br < 0.5f;
        const bool pin    = (bd > 0.5f) && free_r;

        float F0, F1, F2, M0, M1, M2, E0, E1, E2;
        if (AOS) {
            const float4* p = (const float4*)(acc + 16 * (size_t)k);
            const float4 a = p[0], b = p[1], c = p[2];
            F0 = a.x; F1 = a.y; F2 = a.z;
            M0 = a.w; M1 = b.x; M2 = b.y;
            E0 = b.z; E1 = b.w; E2 = c.x;
        } else {
            F0 = acc[3 * k]; F1 = acc[3 * k + 1]; F2 = acc[3 * k + 2];
            M0 = M_soa[3 * k]; M1 = M_soa[3 * k + 1]; M2 = M_soa[3 * k + 2];
            E0 = Fe_soa[3 * k]; E1 = Fe_soa[3 * k + 1]; E2 = Fe_soa[3 * k + 2];
        }

        if (free_d) {
            const float f0 = F0 + E0, f1 = F1 + E1, f2 = F2 + E2;
            sFe2 += (double)(E0 * E0 + E1 * E1 + E2 * E2);
            sF2  += (double)(f0 * f0 + f1 * f1 + f2 * f2);
            cd++;
        }
        if (free_r | pin) {
            const double mm = (double)(M0 * M0 + M1 * M1 + M2 * M2);
            if (free_r) { sMr2 += mm; cr++; }
            if (pin)    { sMp2 += mm; cp++; }
        }
    }

    blockAtomicAddD(sFe2, &sc->Fe2, smD);
    blockAtomicAddD(sF2,  &sc->F2,  smD);
    blockAtomicAddD(sMr2, &sc->Mr2, smD);
    blockAtomicAddD(sMp2, &sc->Mp2, smD);
    blockAtomicAddU(cd, &sc->cnt_d, smU);
    blockAtomicAddU(cr, &sc->cnt_r, smU);
    blockAtomicAddU(cp, &sc->cnt_p, smU);
}

__global__ void finalize(const Scal* sc, float* out, int n_elems)
{
    const double cnt_d = (double)max(sc->cnt_d, 1u);
    const double cnt_r = (double)max(sc->cnt_r, 1u);
    const double cnt_p = (double)max(sc->cnt_p, 1u);

    const double F_char = fmax(sqrt(sc->Fe2 / (cnt_d * 3.0)), 1.0);
    const double L_force = sc->F2 / (cnt_d * 3.0) / (F_char * F_char);

    const double qmax = fmax((double)__uint_as_float(sc->qmax_bits), 1.0);
    const double Lmax = (double)__uint_as_float(sc->Lmax_bits);
    const double M_char = fmax(qmax * Lmax * sc->Lsum / 8.0, 1.0);

    const double L_moment  = sc->Mr2 / (cnt_r * 3.0) / (M_char * M_char);
    const double L_neumann = sc->Mp2 / (cnt_p * 3.0) / (M_char * M_char);

    const double inv_ne = 1.0 / (double)n_elems;
    const double L_kin = sc->rkin2 * inv_ne;
    const double L_consist = sc->e1 * inv_ne + sc->e2 * inv_ne;

    out[0] = (float)(L_force + L_moment + L_neumann + 0.1 * L_kin + L_consist);
}

extern "C" void kernel_launch(void* const* d_in, const int* in_sizes, int n_in,
                              void* d_out, int out_size, void* d_ws, size_t ws_size,
                              hipStream_t stream)
{
    const float* pred     = (const float*)d_in[0];
    const float* grad_ux  = (const float*)d_in[1];
    const float* grad_uz  = (const float*)d_in[2];
    const float* grad_phi = (const float*)d_in[3];
    const float* prop_E   = (const float*)d_in[4];
    const float* prop_A   = (const float*)d_in[5];
    const float* prop_I22 = (const float*)d_in[6];
    const float* elemL    = (const float*)d_in[7];
    const float* dirs     = (const float*)d_in[8];
    const float* load     = (const float*)d_in[9];
    const float* bc_disp  = (const float*)d_in[10];
    const float* bc_rot   = (const float*)d_in[11];
    const int*   conn     = (const int*)d_in[12];

    const int n_elems = in_sizes[4];   // prop_E
    const int n_nodes = in_sizes[10];  // bc_disp (N,1)

    const size_t accA  = (size_t)n_nodes * 64;   // AoS accumulator
    const size_t packB = (size_t)n_nodes * 64;   // packed gather block

    if (ws_size >= packB + accA + 256) {
        // Path A: packed gather + AoS acc
        float* pack = (float*)d_ws;
        float* acc  = (float*)((char*)d_ws + packB);
        Scal*  sc   = (Scal*)((char*)d_ws + packB + accA);
        hipMemsetAsync(acc, 0, accA + sizeof(Scal), stream);
        pack_nodes<<<(n_nodes + 255) / 256, 256, 0, stream>>>(
            pred, grad_ux, grad_uz, grad_phi, pack, n_nodes);
        elem_pass<2><<<4096, 256, 0, stream>>>(
            pred, grad_ux, grad_uz, grad_phi, pack,
            prop_E, prop_A, prop_I22, elemL, dirs, load, conn,
            acc, nullptr, nullptr, sc, n_elems);
        node_pass<true><<<2048, 256, 0, stream>>>(
            acc, nullptr, nullptr, bc_disp, bc_rot, sc, n_nodes);
        finalize<<<1, 1, 0, stream>>>(sc, (float*)d_out, n_elems);
    } else if (ws_size >= accA + 256) {
        // Path B: raw gather + AoS acc
        float* acc = (float*)d_ws;
        Scal*  sc  = (Scal*)((char*)d_ws + accA);
        hipMemsetAsync(acc, 0, accA + sizeof(Scal), stream);
        elem_pass<1><<<4096, 256, 0, stream>>>(
            pred, grad_ux, grad_uz, grad_phi, nullptr,
            prop_E, prop_A, prop_I22, elemL, dirs, load, conn,
            acc, nullptr, nullptr, sc, n_elems);
        node_pass<true><<<2048, 256, 0, stream>>>(
            acc, nullptr, nullptr, bc_disp, bc_rot, sc, n_nodes);
        finalize<<<1, 1, 0, stream>>>(sc, (float*)d_out, n_elems);
    } else {
        // Path C: original SoA layout (36MB + Scal)
        float* F_int = (float*)d_ws;
        float* M_int = F_int + (size_t)3 * n_nodes;
        float* F_ext = M_int + (size_t)3 * n_nodes;
        const size_t node_bytes = (size_t)9 * n_nodes * sizeof(float);
        Scal* sc = (Scal*)((char*)d_ws + node_bytes);
        hipMemsetAsync(d_ws, 0, node_bytes + sizeof(Scal), stream);
        elem_pass<0><<<4096, 256, 0, stream>>>(
            pred, grad_ux, grad_uz, grad_phi, nullptr,
            prop_E, prop_A, prop_I22, elemL, dirs, load, conn,
            F_int, M_int, F_ext, sc, n_elems);
        node_pass<false><<<2048, 256, 0, stream>>>(
            F_int, M_int, F_ext, bc_disp, bc_rot, sc, n_nodes);
        finalize<<<1, 1, 0, stream>>>(sc, (float*)d_out, n_elems);
    }
}

// Round 3
// 695.905 us; speedup vs baseline: 2.9100x; 2.9100x over previous
//
#include <hip/hip_runtime.h>

// ---------------------------------------------------------------------------
// StrongFormPhysicsLoss, round 3: kill the 36M fp32 scatter-atomics.
//   K1 elem_pass : compute per-element payload (streamed write) + count
//                  atomics (4M int) with rank recording; elem reductions
//   K2-K4 scan   : exclusive scan of node degrees (1M u32)
//   K5 fill      : atomic-free CSR entry fill
//   K6 node_pass : per-node gather of payloads + masked reductions
//   K7 finalize  : scalar loss
// Tier1 (ws>=190MB) additionally packs the 4 gathered node arrays [N][16].
// ---------------------------------------------------------------------------

struct Scal {
    double rkin2, e1, e2, Lsum;          // element-level sums
    double Fe2, F2, Mr2, Mp2;            // node-level masked sums
    unsigned int qmax_bits, Lmax_bits;   // float-as-uint maxes (values >= 0)
    unsigned int cnt_d, cnt_r, cnt_p;    // mask counts
};

__device__ __forceinline__ double waveSumD(double v) {
#pragma unroll
    for (int o = 32; o > 0; o >>= 1) v += __shfl_down(v, o, 64);
    return v;
}
__device__ __forceinline__ float waveMaxF(float v) {
#pragma unroll
    for (int o = 32; o > 0; o >>= 1) v = fmaxf(v, __shfl_down(v, o, 64));
    return v;
}
__device__ __forceinline__ unsigned waveSumU(unsigned v) {
#pragma unroll
    for (int o = 32; o > 0; o >>= 1) v += __shfl_down(v, o, 64);
    return v;
}

// block = 256 threads = 4 waves
__device__ __forceinline__ void blockAtomicAddD(double v, double* dst, double* smem) {
    v = waveSumD(v);
    const int lane = threadIdx.x & 63, wid = threadIdx.x >> 6;
    if (lane == 0) smem[wid] = v;
    __syncthreads();
    if (threadIdx.x == 0) atomicAdd(dst, smem[0] + smem[1] + smem[2] + smem[3]);
    __syncthreads();
}
__device__ __forceinline__ void blockAtomicMaxF(float v, unsigned int* dst, float* smem) {
    v = waveMaxF(v);
    const int lane = threadIdx.x & 63, wid = threadIdx.x >> 6;
    if (lane == 0) smem[wid] = v;
    __syncthreads();
    if (threadIdx.x == 0) {
        float r = fmaxf(fmaxf(smem[0], smem[1]), fmaxf(smem[2], smem[3]));
        atomicMax(dst, __float_as_uint(fmaxf(r, 0.0f)));
    }
    __syncthreads();
}
__device__ __forceinline__ void blockAtomicAddU(unsigned v, unsigned int* dst, unsigned* smem) {
    v = waveSumU(v);
    const int lane = threadIdx.x & 63, wid = threadIdx.x >> 6;
    if (lane == 0) smem[wid] = v;
    __syncthreads();
    if (threadIdx.x == 0) atomicAdd(dst, smem[0] + smem[1] + smem[2] + smem[3]);
    __syncthreads();
}

// pack[k][0:3]=pred, [3:6]=grad_ux, [6:9]=grad_uz, [9:12]=grad_phi
__global__ __launch_bounds__(256) void pack_nodes(
    const float* __restrict__ pred, const float* __restrict__ gux,
    const float* __restrict__ guz,  const float* __restrict__ gphi,
    float* __restrict__ pack, int n)
{
    const int k = blockIdx.x * blockDim.x + threadIdx.x;
    if (k >= n) return;
    const size_t b3 = 3 * (size_t)k;
    float4 A = make_float4(pred[b3], pred[b3 + 1], pred[b3 + 2], gux[b3]);
    float4 B = make_float4(gux[b3 + 1], gux[b3 + 2], guz[b3], guz[b3 + 1]);
    float4 C = make_float4(guz[b3 + 2], gphi[b3], gphi[b3 + 1], gphi[b3 + 2]);
    float4* o = (float4*)(pack + 16 * (size_t)k);
    o[0] = A; o[1] = B; o[2] = C;
}

// payload layout per element (12 f32, 48B, 16B-aligned):
//   [0:3]=Fe, [3:6]=M_yi*y, [6:9]=M_yj*y, [9:12]=F_half
template <bool PACKED>
__global__ __launch_bounds__(256) void elem_pass(
    const float* __restrict__ pred, const float* __restrict__ grad_ux,
    const float* __restrict__ grad_uz, const float* __restrict__ grad_phi,
    const float* __restrict__ pack,
    const float* __restrict__ prop_E, const float* __restrict__ prop_A,
    const float* __restrict__ prop_I22, const float* __restrict__ elemL,
    const float* __restrict__ dirs, const float* __restrict__ load,
    const int* __restrict__ conn,
    float* __restrict__ payload,
    unsigned int* __restrict__ counts,
    unsigned char* __restrict__ pos,
    Scal* sc, int n_elems)
{
    __shared__ double smD[4];
    __shared__ float  smF[4];

    double s_rkin2 = 0.0, s_e1 = 0.0, s_e2 = 0.0, s_Lsum = 0.0;
    float m_q = 0.0f, m_L = 0.0f;

    const int stride = gridDim.x * blockDim.x;
    for (int e = blockIdx.x * blockDim.x + threadIdx.x; e < n_elems; e += stride) {
        const int2 ij = ((const int2*)conn)[e];
        const int i = ij.x, j = ij.y;

        const float x0 = dirs[3 * e], x1 = dirs[3 * e + 1], x2 = dirs[3 * e + 2];

        // local axes
        const bool par = fabsf(x1) > 0.99f;
        float z0, z1, z2;
        if (par) { z0 = x1; z1 = -x0; z2 = 0.0f; }      // cross(x,(0,0,1))
        else     { z0 = -x2; z1 = 0.0f; z2 = x0; }      // cross(x,(0,1,0))
        float zn = fmaxf(sqrtf(z0 * z0 + z1 * z1 + z2 * z2), 1e-8f);
        z0 /= zn; z1 /= zn; z2 /= zn;
        float y0 = z1 * x2 - z2 * x1;
        float y1 = z2 * x0 - z0 * x2;
        float y2 = z0 * x1 - z1 * x0;
        float yn = fmaxf(sqrtf(y0 * y0 + y1 * y1 + y2 * y2), 1e-8f);
        y0 /= yn; y1 /= yn; y2 /= yn;

        // node gathers
        float uxi, uzi, phii, uxj, uzj, phij;
        float gxi, gzi, kap_i, gxj, gzj, kap_j;
        if (PACKED) {
            const float4* pi = (const float4*)(pack + 16 * (size_t)i);
            const float4 a = pi[0], b = pi[1], c = pi[2];
            uxi = a.x; uzi = a.y; phii = a.z;
            gxi   = a.w * x0 + b.x * x1 + b.y * x2;
            gzi   = b.z * x0 + b.w * x1 + c.x * x2;
            kap_i = c.y * x0 + c.z * x1 + c.w * x2;
            const float4* pj = (const float4*)(pack + 16 * (size_t)j);
            const float4 d = pj[0], f = pj[1], g = pj[2];
            uxj = d.x; uzj = d.y; phij = d.z;
            gxj   = d.w * x0 + f.x * x1 + f.y * x2;
            gzj   = f.z * x0 + f.w * x1 + g.x * x2;
            kap_j = g.y * x0 + g.z * x1 + g.w * x2;
        } else {
            uxi = pred[3 * i]; uzi = pred[3 * i + 1]; phii = pred[3 * i + 2];
            uxj = pred[3 * j]; uzj = pred[3 * j + 1]; phij = pred[3 * j + 2];
            gxi   = grad_ux[3 * i] * x0 + grad_ux[3 * i + 1] * x1 + grad_ux[3 * i + 2] * x2;
            gzi   = grad_uz[3 * i] * x0 + grad_uz[3 * i + 1] * x1 + grad_uz[3 * i + 2] * x2;
            kap_i = grad_phi[3 * i] * x0 + grad_phi[3 * i + 1] * x1 + grad_phi[3 * i + 2] * x2;
            gxj   = grad_ux[3 * j] * x0 + grad_ux[3 * j + 1] * x1 + grad_ux[3 * j + 2] * x2;
            gzj   = grad_uz[3 * j] * x0 + grad_uz[3 * j + 1] * x1 + grad_uz[3 * j + 2] * x2;
            kap_j = grad_phi[3 * j] * x0 + grad_phi[3 * j + 1] * x1 + grad_phi[3 * j + 2] * x2;
        }
        const float dux = uxj - uxi, duz = uzj - uzi;

        const float Le   = elemL[e];
        const float invL = 1.0f / Le;
        const float EA   = prop_E[e] * prop_A[e];
        const float EI   = prop_E[e] * prop_I22[e];

        const float du_ax  = dux * x0 + duz * x2;
        const float eps_fd = du_ax * invL;
        const float N_fd   = EA * eps_fd;
        const float du_tr  = dux * z0 + duz * z2;
        const float kappa_fd = (phij - phii) * invL;

        const float EIL = EI * invL, EIL2 = EIL * invL, EIL3 = EIL2 * invL;
        const float V_fd = 12.0f * EIL3 * du_tr - 6.0f * EIL2 * (phii + phij);
        const float M_yi = 6.0f * EIL2 * du_tr - EIL * (4.0f * phii + 2.0f * phij);
        const float M_yj = 6.0f * EIL2 * du_tr - EIL * (2.0f * phii + 4.0f * phij);

        const float eps_ag   = 0.5f * ((x0 * gxi + x2 * gzi) + (x0 * gxj + x2 * gzj));
        const float kappa_ag = 0.5f * (kap_i + kap_j);

        const float Fe0 = N_fd * x0 + V_fd * z0;
        const float Fe1 = N_fd * x1 + V_fd * z1;
        const float Fe2 = N_fd * x2 + V_fd * z2;

        const float l0 = load[3 * e], l1 = load[3 * e + 1], l2 = load[3 * e + 2];
        const float hl = 0.5f * Le;

        // payload write (streamed, 3x float4)
        float4* pw = (float4*)(payload + 12 * (size_t)e);
        pw[0] = make_float4(Fe0, Fe1, Fe2, M_yi * y0);
        pw[1] = make_float4(M_yi * y1, M_yi * y2, M_yj * y0, M_yj * y1);
        pw[2] = make_float4(M_yj * y2, l0 * hl, l1 * hl, l2 * hl);

        // degree count + rank record (the ONLY scattered atomics: 2 per elem)
        pos[2 * e]     = (unsigned char)atomicAdd(&counts[i], 1u);
        pos[2 * e + 1] = (unsigned char)atomicAdd(&counts[j], 1u);

        // element-level reductions
        const float dw_ds = du_tr * invL;
        const float r_kin = 0.5f * (phii + phij) - dw_ds;
        s_rkin2 += (double)(r_kin * r_kin);
        const float d1 = eps_ag - eps_fd;
        s_e1 += (double)(d1 * d1);
        const float d2 = kappa_ag - kappa_fd;
        s_e2 += (double)(d2 * d2);
        s_Lsum += (double)Le;
        m_q = fmaxf(m_q, fmaxf(fabsf(l0), fmaxf(fabsf(l1), fabsf(l2))));
        m_L = fmaxf(m_L, Le);
    }

    blockAtomicAddD(s_rkin2, &sc->rkin2, smD);
    blockAtomicAddD(s_e1,    &sc->e1,    smD);
    blockAtomicAddD(s_e2,    &sc->e2,    smD);
    blockAtomicAddD(s_Lsum,  &sc->Lsum,  smD);
    blockAtomicMaxF(m_q, &sc->qmax_bits, smF);
    blockAtomicMaxF(m_L, &sc->Lmax_bits, smF);
}

// --- exclusive scan of counts[n] -> offs[n], 3 kernels ---------------------
__global__ __launch_bounds__(256) void scan1(
    const unsigned int* __restrict__ counts, unsigned int* __restrict__ partial, int n)
{
    __shared__ unsigned smU[4];
    const int idx = blockIdx.x * 256 + threadIdx.x;
    unsigned v = (idx < n) ? counts[idx] : 0u;
    v = waveSumU(v);
    const int lane = threadIdx.x & 63, wid = threadIdx.x >> 6;
    if (lane == 0) smU[wid] = v;
    __syncthreads();
    if (threadIdx.x == 0) partial[blockIdx.x] = smU[0] + smU[1] + smU[2] + smU[3];
}

// single block, 1024 threads, nblk <= 4096: in-place exclusive scan of partial[]
__global__ __launch_bounds__(1024) void scan2(unsigned int* partial, int nblk)
{
    __shared__ unsigned sm[1024];
    const int t = threadIdx.x;
    const int base = t * 4;
    unsigned v[4];
    unsigned run = 0;
#pragma unroll
    for (int c = 0; c < 4; ++c) {
        unsigned x = (base + c < nblk) ? partial[base + c] : 0u;
        v[c] = run;            // exclusive within chunk
        run += x;
    }
    sm[t] = run;
    __syncthreads();
    // Hillis-Steele inclusive scan over 1024 chunk sums
    for (int off = 1; off < 1024; off <<= 1) {
        unsigned x = (t >= off) ? sm[t - off] : 0u;
        __syncthreads();
        sm[t] += x;
        __syncthreads();
    }
    const unsigned chunkExcl = (t == 0) ? 0u : sm[t - 1];
#pragma unroll
    for (int c = 0; c < 4; ++c)
        if (base + c < nblk) partial[base + c] = chunkExcl + v[c];
}

__global__ __launch_bounds__(256) void scan3(
    const unsigned int* __restrict__ counts, const unsigned int* __restrict__ partial,
    unsigned int* __restrict__ offs, int n)
{
    __shared__ unsigned sm[256];
    const int t = threadIdx.x;
    const int idx = blockIdx.x * 256 + t;
    const unsigned v = (idx < n) ? counts[idx] : 0u;
    sm[t] = v;
    __syncthreads();
    for (int off = 1; off < 256; off <<= 1) {
        unsigned x = (t >= off) ? sm[t - off] : 0u;
        __syncthreads();
        sm[t] += x;
        __syncthreads();
    }
    if (idx < n) offs[idx] = (sm[t] - v) + partial[blockIdx.x];
}

// atomic-free CSR fill: entries[offs[node] + rank] = (e<<1)|side
__global__ __launch_bounds__(256) void fill_entries(
    const int* __restrict__ conn, const unsigned char* __restrict__ pos,
    const unsigned int* __restrict__ offs, unsigned int* __restrict__ entries,
    int n_elems)
{
    const int stride = gridDim.x * blockDim.x;
    for (int e = blockIdx.x * blockDim.x + threadIdx.x; e < n_elems; e += stride) {
        const int2 ij = ((const int2*)conn)[e];
        entries[offs[ij.x] + pos[2 * e]]     = ((unsigned)e << 1);
        entries[offs[ij.y] + pos[2 * e + 1]] = ((unsigned)e << 1) | 1u;
    }
}

__global__ __launch_bounds__(256) void node_pass(
    const float* __restrict__ payload,
    const unsigned int* __restrict__ offs, const unsigned int* __restrict__ counts,
    const unsigned int* __restrict__ entries,
    const float* __restrict__ bc_disp, const float* __restrict__ bc_rot,
    Scal* sc, int n_nodes)
{
    __shared__ double smD[4];
    __shared__ unsigned smU[4];

    double sFe2 = 0.0, sF2 = 0.0, sMr2 = 0.0, sMp2 = 0.0;
    unsigned cd = 0, cr = 0, cp = 0;

    const int stride = gridDim.x * blockDim.x;
    for (int k = blockIdx.x * blockDim.x + threadIdx.x; k < n_nodes; k += stride) {
        const unsigned base = offs[k];
        const unsigned deg  = counts[k];

        float F0 = 0.f, F1 = 0.f, F2 = 0.f;
        float M0 = 0.f, M1 = 0.f, M2 = 0.f;
        float E0 = 0.f, E1 = 0.f, E2 = 0.f;

        for (unsigned d = 0; d < deg; ++d) {
            const unsigned idx = entries[base + d];
            const unsigned e = idx >> 1;
            const bool side_j = idx & 1u;
            const float4* p = (const float4*)(payload + 12 * (size_t)e);
            const float4 a = p[0], b = p[1], c = p[2];
            // a = (Fe0,Fe1,Fe2,Mi0)  b = (Mi1,Mi2,Mj0,Mj1)  c = (Mj2,Fh0,Fh1,Fh2)
            const float sgn = side_j ? -1.0f : 1.0f;
            F0 += sgn * a.x; F1 += sgn * a.y; F2 += sgn * a.z;
            if (side_j) { M0 += b.z; M1 += b.w; M2 += c.x; }
            else        { M0 += a.w; M1 += b.x; M2 += b.y; }
            E0 += c.y; E1 += c.z; E2 += c.w;
        }

        const float bd = bc_disp[k], br = bc_rot[k];
        const bool free_d = bd < 0.5f;
        const bool free_r = br < 0.5f;
        const bool pin    = (bd > 0.5f) && free_r;

        if (free_d) {
            const float f0 = F0 + E0, f1 = F1 + E1, f2 = F2 + E2;
            sFe2 += (double)(E0 * E0 + E1 * E1 + E2 * E2);
            sF2  += (double)(f0 * f0 + f1 * f1 + f2 * f2);
            cd++;
        }
        if (free_r | pin) {
            const double mm = (double)(M0 * M0 + M1 * M1 + M2 * M2);
            if (free_r) { sMr2 += mm; cr++; }
            if (pin)    { sMp2 += mm; cp++; }
        }
    }

    blockAtomicAddD(sFe2, &sc->Fe2, smD);
    blockAtomicAddD(sF2,  &sc->F2,  smD);
    blockAtomicAddD(sMr2, &sc->Mr2, smD);
    blockAtomicAddD(sMp2, &sc->Mp2, smD);
    blockAtomicAddU(cd, &sc->cnt_d, smU);
    blockAtomicAddU(cr, &sc->cnt_r, smU);
    blockAtomicAddU(cp, &sc->cnt_p, smU);
}

__global__ void finalize(const Scal* sc, float* out, int n_elems)
{
    const double cnt_d = (double)max(sc->cnt_d, 1u);
    const double cnt_r = (double)max(sc->cnt_r, 1u);
    const double cnt_p = (double)max(sc->cnt_p, 1u);

    const double F_char = fmax(sqrt(sc->Fe2 / (cnt_d * 3.0)), 1.0);
    const double L_force = sc->F2 / (cnt_d * 3.0) / (F_char * F_char);

    const double qmax = fmax((double)__uint_as_float(sc->qmax_bits), 1.0);
    const double Lmax = (double)__uint_as_float(sc->Lmax_bits);
    const double M_char = fmax(qmax * Lmax * sc->Lsum / 8.0, 1.0);

    const double L_moment  = sc->Mr2 / (cnt_r * 3.0) / (M_char * M_char);
    const double L_neumann = sc->Mp2 / (cnt_p * 3.0) / (M_char * M_char);

    const double inv_ne = 1.0 / (double)n_elems;
    const double L_kin = sc->rkin2 * inv_ne;
    const double L_consist = sc->e1 * inv_ne + sc->e2 * inv_ne;

    out[0] = (float)(L_force + L_moment + L_neumann + 0.1 * L_kin + L_consist);
}

extern "C" void kernel_launch(void* const* d_in, const int* in_sizes, int n_in,
                              void* d_out, int out_size, void* d_ws, size_t ws_size,
                              hipStream_t stream)
{
    const float* pred     = (const float*)d_in[0];
    const float* grad_ux  = (const float*)d_in[1];
    const float* grad_uz  = (const float*)d_in[2];
    const float* grad_phi = (const float*)d_in[3];
    const float* prop_E   = (const float*)d_in[4];
    const float* prop_A   = (const float*)d_in[5];
    const float* prop_I22 = (const float*)d_in[6];
    const float* elemL    = (const float*)d_in[7];
    const float* dirs     = (const float*)d_in[8];
    const float* load     = (const float*)d_in[9];
    const float* bc_disp  = (const float*)d_in[10];
    const float* bc_rot   = (const float*)d_in[11];
    const int*   conn     = (const int*)d_in[12];

    const int n_elems = in_sizes[4];   // prop_E
    const int n_nodes = in_sizes[10];  // bc_disp (N,1)
    const int nblk256 = (n_nodes + 255) / 256;   // <= 4096 for N <= 1,048,576

    const size_t szPayload = (size_t)n_elems * 12 * sizeof(float); // 96MB
    const size_t szCounts  = (size_t)n_nodes * sizeof(unsigned);   // 4MB
    const size_t szOffs    = szCounts;                             // 4MB
    const size_t szPos     = (size_t)n_elems * 2;                  // 4MB
    const size_t szEntries = (size_t)n_elems * 2 * sizeof(unsigned); // 16MB
    const size_t szPartial = 4096 * sizeof(unsigned);
    const size_t szPack    = (size_t)n_nodes * 64;                 // 64MB

    const size_t csrCore = szPayload + szCounts + szOffs + szPos + szEntries +
                           szPartial + sizeof(Scal) + 64;

    char* base = (char*)d_ws;
    const bool usePack = (ws_size >= csrCore + szPack);

    float* pack = nullptr;
    if (usePack) { pack = (float*)base; base += szPack; }
    float*         payload = (float*)base;            base += szPayload;
    unsigned int*  counts  = (unsigned int*)base;     base += szCounts;
    unsigned int*  offs    = (unsigned int*)base;     base += szOffs;
    unsigned char* pos     = (unsigned char*)base;    base += szPos;
    unsigned int*  entries = (unsigned int*)base;     base += szEntries;
    unsigned int*  partial = (unsigned int*)base;     base += szPartial;
    Scal*          sc      = (Scal*)base;

    // zero only counts + Scal (everything else fully overwritten)
    hipMemsetAsync(counts, 0, szCounts, stream);
    hipMemsetAsync(sc, 0, sizeof(Scal), stream);

    if (usePack) {
        pack_nodes<<<nblk256, 256, 0, stream>>>(
            pred, grad_ux, grad_uz, grad_phi, pack, n_nodes);
        elem_pass<true><<<4096, 256, 0, stream>>>(
            pred, grad_ux, grad_uz, grad_phi, pack,
            prop_E, prop_A, prop_I22, elemL, dirs, load, conn,
            payload, counts, pos, sc, n_elems);
    } else {
        elem_pass<false><<<4096, 256, 0, stream>>>(
            pred, grad_ux, grad_uz, grad_phi, nullptr,
            prop_E, prop_A, prop_I22, elemL, dirs, load, conn,
            payload, counts, pos, sc, n_elems);
    }

    scan1<<<nblk256, 256, 0, stream>>>(counts, partial, n_nodes);
    scan2<<<1, 1024, 0, stream>>>(partial, nblk256);
    scan3<<<nblk256, 256, 0, stream>>>(counts, partial, offs, n_nodes);

    fill_entries<<<4096, 256, 0, stream>>>(conn, pos, offs, entries, n_elems);

    node_pass<<<nblk256, 256, 0, stream>>>(
        payload, offs, counts, entries, bc_disp, bc_rot, sc, n_nodes);

    finalize<<<1, 1, 0, stream>>>(sc, (float*)d_out, n_elems);
}